// Round 8
// baseline (685.490 us; speedup 1.0000x reference)
//
#include <hip/hip_runtime.h>
#include <stdint.h>

#define TT 128
#define BSZ 512
#define HID 512
#define KDIM 512
#define BH (BSZ*HID)   // 262144 neurons

// ---------------- fp32 tiled GEMM: C[m][n] = sum_k A[m][k] * W[n][k] + bias[n] --------
// v9 gemm = v3 VERBATIM (measured best: 403us). Evidence from v1-v8:
//  - v3: 128x256 tile, 8x16 microtile, BK=16, dbuf, 1 barrier/tile; A reads are
//    16-lane-broadcast b128, B reads 4-lane-broadcast b128 -> ~0.13 cyc/read conflict
//    overhead (6.29M cycles / ~50M b128) => NOT LDS-bound. VALU busy 282us vs 218us
//    pure-fma floor; ~120us idle. 403us.
//  - v4 pk_fma: rate-neutral per FLOP on CDNA4 (fewer instrs, same cycles) -> 431us.
//  - v5 (A via s_load): out-of-order scalar loads force lgkmcnt(0) drains -> 437us.
//  - v6 (b32 B reads): 4x LDS instr count -> ~530us. v7: (256,4) spill -> 911us.
//  - v8 (A in LDS, per-lane-distinct B b128): truly LDS-bound 1.5x -> 471us.
// Departures from v3 in every direction regressed; treat as closed.
// NUMERICS CONTRACT (bit-exact vs np ref, absmax 0.0): per output element the
// reduction is ONE sequential fp32 fma chain over k ascending. Do not reorder/split.
__global__ __launch_bounds__(256, 1) void gemm_f32(
    const float* __restrict__ A, const float* __restrict__ W,
    const float* __restrict__ bias, float* __restrict__ C) {
  __shared__ float As[2][16][132];   // [buf][k][m], +4/row bank shift
  __shared__ float Bs[2][16][260];   // [buf][k][n], +4/row bank shift
  const int t  = threadIdx.x;
  const int m0 = blockIdx.y * 128;
  const int n0 = blockIdx.x * 256;
  const int tx = t & 15;          // n group: cols {tx*4..+3} in each 64-wide quarter
  const int ty = t >> 4;          // m group: rows ty*8..ty*8+7
  const int r0 = t >> 2;          // staging row 0..63 (+64/128/192 replicas)
  const int kg = t & 3;           // k float4 group within 16-wide k tile

  float acc[8][16];
  #pragma unroll
  for (int i = 0; i < 8; ++i)
    #pragma unroll
    for (int j = 0; j < 16; ++j) acc[i][j] = 0.f;

  const float* Ap = A + (size_t)(m0 + r0) * KDIM + kg * 4;
  const float* Wp = W + (size_t)(n0 + r0) * KDIM + kg * 4;

  float4 a0 = *(const float4*)Ap;
  float4 a1 = *(const float4*)(Ap + (size_t)64  * KDIM);
  float4 w0 = *(const float4*)Wp;
  float4 w1 = *(const float4*)(Wp + (size_t)64  * KDIM);
  float4 w2 = *(const float4*)(Wp + (size_t)128 * KDIM);
  float4 w3 = *(const float4*)(Wp + (size_t)192 * KDIM);

  // stage tile into buffer BUF (24 b32 scatter writes; 2-way bank alias only -> free)
  #define STAGE(BUF) do { \
    As[BUF][kg*4+0][r0]     = a0.x; As[BUF][kg*4+1][r0]     = a0.y; \
    As[BUF][kg*4+2][r0]     = a0.z; As[BUF][kg*4+3][r0]     = a0.w; \
    As[BUF][kg*4+0][r0+64]  = a1.x; As[BUF][kg*4+1][r0+64]  = a1.y; \
    As[BUF][kg*4+2][r0+64]  = a1.z; As[BUF][kg*4+3][r0+64]  = a1.w; \
    Bs[BUF][kg*4+0][r0]     = w0.x; Bs[BUF][kg*4+1][r0]     = w0.y; \
    Bs[BUF][kg*4+2][r0]     = w0.z; Bs[BUF][kg*4+3][r0]     = w0.w; \
    Bs[BUF][kg*4+0][r0+64]  = w1.x; Bs[BUF][kg*4+1][r0+64]  = w1.y; \
    Bs[BUF][kg*4+2][r0+64]  = w1.z; Bs[BUF][kg*4+3][r0+64]  = w1.w; \
    Bs[BUF][kg*4+0][r0+128] = w2.x; Bs[BUF][kg*4+1][r0+128] = w2.y; \
    Bs[BUF][kg*4+2][r0+128] = w2.z; Bs[BUF][kg*4+3][r0+128] = w2.w; \
    Bs[BUF][kg*4+0][r0+192] = w3.x; Bs[BUF][kg*4+1][r0+192] = w3.y; \
    Bs[BUF][kg*4+2][r0+192] = w3.z; Bs[BUF][kg*4+3][r0+192] = w3.w; \
  } while (0)

  STAGE(0);

  int cur = 0;
  for (int k0 = 0; k0 < KDIM; k0 += 16) {
    // Single barrier per tile. Drains lgkmcnt -> (a) buf[cur] writes visible,
    // (b) previous iteration's ds_reads of buf[cur^1] complete, so staging into
    // buf[cur^1] below is safe.
    __syncthreads();
    const bool more = (k0 + 16 < KDIM);
    if (more) {   // global prefetch of next tile; latency hidden under the fma block
      a0 = *(const float4*)(Ap + k0 + 16);
      a1 = *(const float4*)(Ap + (size_t)64  * KDIM + k0 + 16);
      w0 = *(const float4*)(Wp + k0 + 16);
      w1 = *(const float4*)(Wp + (size_t)64  * KDIM + k0 + 16);
      w2 = *(const float4*)(Wp + (size_t)128 * KDIM + k0 + 16);
      w3 = *(const float4*)(Wp + (size_t)192 * KDIM + k0 + 16);
    }

    #pragma unroll
    for (int kk = 0; kk < 16; ++kk) {
      const float4 xa0 = *(const float4*)&As[cur][kk][ty*8];        // broadcast x16 lanes
      const float4 xa1 = *(const float4*)&As[cur][kk][ty*8 + 4];
      const float a[8] = {xa0.x,xa0.y,xa0.z,xa0.w,xa1.x,xa1.y,xa1.z,xa1.w};
      // One B-quarter (4 regs) live at a time. Per-acc-element k-order unchanged.
      #pragma unroll
      for (int q = 0; q < 4; ++q) {
        const float4 xb = *(const float4*)&Bs[cur][kk][64*q + tx*4]; // 4-lane bcast: free
        #pragma unroll
        for (int i = 0; i < 8; ++i) {
          acc[i][q*4+0] = __builtin_fmaf(a[i], xb.x, acc[i][q*4+0]);
          acc[i][q*4+1] = __builtin_fmaf(a[i], xb.y, acc[i][q*4+1]);
          acc[i][q*4+2] = __builtin_fmaf(a[i], xb.z, acc[i][q*4+2]);
          acc[i][q*4+3] = __builtin_fmaf(a[i], xb.w, acc[i][q*4+3]);
        }
      }
    }

    if (more) {
      const int nb = cur ^ 1;
      STAGE(nb);      // overlaps other waves' compute; protected by next barrier
    }
    cur ^= 1;
  }
  #undef STAGE

  // epilogue: + bias (ref adds b once to xp — identical), coalesced float4 stores
  float4 bv[4];
  #pragma unroll
  for (int q = 0; q < 4; ++q) bv[q] = *(const float4*)&bias[n0 + 64*q + tx*4];
  #pragma unroll
  for (int i = 0; i < 8; ++i) {
    float* cp = C + (size_t)(m0 + ty*8 + i) * HID + n0 + tx*4;
    #pragma unroll
    for (int q = 0; q < 4; ++q) {
      const float4 v = {acc[i][q*4+0] + bv[q].x, acc[i][q*4+1] + bv[q].y,
                        acc[i][q*4+2] + bv[q].z, acc[i][q*4+3] + bv[q].w};
      *(float4*)(cp + 64*q) = v;
    }
  }
}

// ---------------- LIF scan: wave-synchronous 4-layer pipeline ----------------
// v9: old lif (1 thread = 1 neuron, 4 layers serial) ran ~165-195us vs ~55us issue
// floor: latency-chain-bound (per t: 4 layers x 4 substeps serial, ~400+ cyc chain vs
// ~240 issue-cyc) at only 4 waves/SIMD (1024 blocks). Split layers across lanes:
// lane = (neuron q = lane>>2, layer l = lane&3). Layer l processes time t = s - l at
// pipeline step s; handoff avg_v (layer l-1 -> l) via __shfl_up(.,1,4) = bit-exact
// register move. Receiver (layer l, step s+1, needs t=s+1-l) uses sender's (l-1) value
// from step s (t = s-(l-1) = s+1-l ✓). 4x waves (4096 blocks -> 8 waves/SIMD), 1/4 the
// per-wave chain, same instruction total. Per-neuron-layer arithmetic order IDENTICAL
// to the reference chain -> absmax 0.0. Boundary steps are predicated no-ops; xp ring
// uses static indices only (runtime-indexed reg arrays go to scratch).
__global__ __launch_bounds__(256) void lif_scan(
    const float* __restrict__ xp, float* __restrict__ outp, float* __restrict__ vstate,
    int tc, int first, int last) {
  const int t    = threadIdx.x;
  const int lane = t & 63;
  const int l    = lane & 3;                                   // layer 0..3
  const int nidx = blockIdx.x * 64 + (t >> 6) * 16 + (lane >> 2);  // neuron
  const float* px = xp + nidx;
  float* op = outp + nidx;

  float v    = 0.f;
  if (!first) v = vstate[(size_t)l * BH + nidx];
  float avr  = 0.f;   // last committed avg_v (handoff source + final-state store)
  float hand = 0.f;   // neighbor's (layer l-1) avg_v from previous step

  // 4-deep xp ring; all 4 layer-lanes of a neuron load the same addr (coalesced).
  float xq[4];
  #pragma unroll
  for (int i = 0; i < 4; ++i) xq[i] = px[(size_t)(i < tc ? i : 0) * BH];

  const int S = tc + 3;   // pipeline steps (plus up to 3 predicated no-op tail steps)

  #define LSTEP(J) do { \
    const int s = s0 + (J); \
    const float y0 = xq[J]; \
    { const int sp = s + 4; if (sp < tc) xq[J] = px[(size_t)sp * BH]; } \
    const float y = (l == 0) ? y0 : hand; \
    float vv = v, accv = 0.f, accs = 0.f; \
    _Pragma("unroll") \
    for (int k = 0; k < 4; ++k) { \
      const float d = y - vv;                        /* round(inp - v) */ \
      vv = __builtin_fmaf(d, 0.5f, vv);              /* round(v + d*0.5) */ \
      const float spk = (vv >= 1.0f) ? 1.0f : 0.0f;  /* exact threshold */ \
      vv -= spk;                                     /* soft reset */ \
      accv += vv; \
      accs += spk; \
    } \
    const float av_new = accv * 0.25f;               /* exact /4 */ \
    const bool act = (s >= l) && ((s - l) < tc); \
    v   = act ? vv : v; \
    avr = act ? av_new : avr; \
    hand = __shfl_up(avr, 1, 4); \
    if (l == 3 && act) \
      __builtin_nontemporal_store(accs * 0.25f, op + (size_t)(s - 3) * BH); \
  } while (0)

  for (int s0 = 0; s0 < S; s0 += 4) {
    LSTEP(0); LSTEP(1); LSTEP(2); LSTEP(3);
  }
  #undef LSTEP

  if (last) vstate[(size_t)l * BH + nidx] = avr;   // final avg_v per layer
  else      vstate[(size_t)l * BH + nidx] = v;     // chunk-carry membrane state
}

extern "C" void kernel_launch(void* const* d_in, const int* in_sizes, int n_in,
                              void* d_out, int out_size, void* d_ws, size_t ws_size,
                              hipStream_t stream) {
  const float* x = (const float*)d_in[0];   // [128,512,512] fp32
  const float* W = (const float*)d_in[1];   // [512,512] fp32
  const float* b = (const float*)d_in[2];   // [512] fp32
  float* out    = (float*)d_out;            // [128,512,512] avg spikes (fp32)
  float* states = out + (size_t)TT * BH;    // [4,512,512] final avg_v; also chunk-carry v

  int tc = TT;                              // xp chunk: tc MiB of ws
  while (tc > 1 && (size_t)tc * BH * 4ull > ws_size) tc >>= 1;
  float* xp = (float*)d_ws;
  const int nc = TT / tc;

  for (int c = 0; c < nc; ++c) {
    hipLaunchKernelGGL(gemm_f32, dim3(HID / 256, tc * BSZ / 128), dim3(256), 0, stream,
                       x + (size_t)c * tc * BH, W, b, xp);
    hipLaunchKernelGGL(lif_scan, dim3(BH / 64), dim3(256), 0, stream,
                       xp, out + (size_t)c * tc * BH, states,
                       tc, c == 0 ? 1 : 0, c == nc - 1 ? 1 : 0);
  }
}

// Round 9
// 596.706 us; speedup vs baseline: 1.1488x; 1.1488x over previous
//
#include <hip/hip_runtime.h>
#include <stdint.h>

#define TT 128
#define BSZ 512
#define HID 512
#define KDIM 512
#define BH (BSZ*HID)   // 262144 neurons

// ---------------- fp32 tiled GEMM: C[m][n] = sum_k A[m][k] * W[n][k] + bias[n] --------
// v10 gemm = v9 VERBATIM (measured best: 388us @ (256,1); v3 structure).
// Evidence v1-v9: VALU busy-time invariant ~282us across ALL structures (pure-fma floor
// 218us); pk_fma rate-neutral (431); A-via-s_load lgkm drains (437); b32 B reads (530);
// (256,4) spill (911); A-in-LDS distinct-b128 truly LDS-bound (471). 128x256 tile,
// 8x16 microtile, BK=16, dbuf, 1 barrier/tile, broadcast LDS reads = measured optimum.
// NUMERICS CONTRACT (bit-exact vs np ref, absmax 0.0): per output element the
// reduction is ONE sequential fp32 fma chain over k ascending. Do not reorder/split.
__global__ __launch_bounds__(256, 1) void gemm_f32(
    const float* __restrict__ A, const float* __restrict__ W,
    const float* __restrict__ bias, float* __restrict__ C) {
  __shared__ float As[2][16][132];   // [buf][k][m], +4/row bank shift
  __shared__ float Bs[2][16][260];   // [buf][k][n], +4/row bank shift
  const int t  = threadIdx.x;
  const int m0 = blockIdx.y * 128;
  const int n0 = blockIdx.x * 256;
  const int tx = t & 15;          // n group: cols {tx*4..+3} in each 64-wide quarter
  const int ty = t >> 4;          // m group: rows ty*8..ty*8+7
  const int r0 = t >> 2;          // staging row 0..63 (+64/128/192 replicas)
  const int kg = t & 3;           // k float4 group within 16-wide k tile

  float acc[8][16];
  #pragma unroll
  for (int i = 0; i < 8; ++i)
    #pragma unroll
    for (int j = 0; j < 16; ++j) acc[i][j] = 0.f;

  const float* Ap = A + (size_t)(m0 + r0) * KDIM + kg * 4;
  const float* Wp = W + (size_t)(n0 + r0) * KDIM + kg * 4;

  float4 a0 = *(const float4*)Ap;
  float4 a1 = *(const float4*)(Ap + (size_t)64  * KDIM);
  float4 w0 = *(const float4*)Wp;
  float4 w1 = *(const float4*)(Wp + (size_t)64  * KDIM);
  float4 w2 = *(const float4*)(Wp + (size_t)128 * KDIM);
  float4 w3 = *(const float4*)(Wp + (size_t)192 * KDIM);

  // stage tile into buffer BUF (24 b32 scatter writes; 2-way bank alias only -> free)
  #define STAGE(BUF) do { \
    As[BUF][kg*4+0][r0]     = a0.x; As[BUF][kg*4+1][r0]     = a0.y; \
    As[BUF][kg*4+2][r0]     = a0.z; As[BUF][kg*4+3][r0]     = a0.w; \
    As[BUF][kg*4+0][r0+64]  = a1.x; As[BUF][kg*4+1][r0+64]  = a1.y; \
    As[BUF][kg*4+2][r0+64]  = a1.z; As[BUF][kg*4+3][r0+64]  = a1.w; \
    Bs[BUF][kg*4+0][r0]     = w0.x; Bs[BUF][kg*4+1][r0]     = w0.y; \
    Bs[BUF][kg*4+2][r0]     = w0.z; Bs[BUF][kg*4+3][r0]     = w0.w; \
    Bs[BUF][kg*4+0][r0+64]  = w1.x; Bs[BUF][kg*4+1][r0+64]  = w1.y; \
    Bs[BUF][kg*4+2][r0+64]  = w1.z; Bs[BUF][kg*4+3][r0+64]  = w1.w; \
    Bs[BUF][kg*4+0][r0+128] = w2.x; Bs[BUF][kg*4+1][r0+128] = w2.y; \
    Bs[BUF][kg*4+2][r0+128] = w2.z; Bs[BUF][kg*4+3][r0+128] = w2.w; \
    Bs[BUF][kg*4+0][r0+192] = w3.x; Bs[BUF][kg*4+1][r0+192] = w3.y; \
    Bs[BUF][kg*4+2][r0+192] = w3.z; Bs[BUF][kg*4+3][r0+192] = w3.w; \
  } while (0)

  STAGE(0);

  int cur = 0;
  for (int k0 = 0; k0 < KDIM; k0 += 16) {
    // Single barrier per tile. Drains lgkmcnt -> (a) buf[cur] writes visible,
    // (b) previous iteration's ds_reads of buf[cur^1] complete, so staging into
    // buf[cur^1] below is safe.
    __syncthreads();
    const bool more = (k0 + 16 < KDIM);
    if (more) {   // global prefetch of next tile; latency hidden under the fma block
      a0 = *(const float4*)(Ap + k0 + 16);
      a1 = *(const float4*)(Ap + (size_t)64  * KDIM + k0 + 16);
      w0 = *(const float4*)(Wp + k0 + 16);
      w1 = *(const float4*)(Wp + (size_t)64  * KDIM + k0 + 16);
      w2 = *(const float4*)(Wp + (size_t)128 * KDIM + k0 + 16);
      w3 = *(const float4*)(Wp + (size_t)192 * KDIM + k0 + 16);
    }

    #pragma unroll
    for (int kk = 0; kk < 16; ++kk) {
      const float4 xa0 = *(const float4*)&As[cur][kk][ty*8];        // broadcast x16 lanes
      const float4 xa1 = *(const float4*)&As[cur][kk][ty*8 + 4];
      const float a[8] = {xa0.x,xa0.y,xa0.z,xa0.w,xa1.x,xa1.y,xa1.z,xa1.w};
      // One B-quarter (4 regs) live at a time. Per-acc-element k-order unchanged.
      #pragma unroll
      for (int q = 0; q < 4; ++q) {
        const float4 xb = *(const float4*)&Bs[cur][kk][64*q + tx*4]; // 4-lane bcast: free
        #pragma unroll
        for (int i = 0; i < 8; ++i) {
          acc[i][q*4+0] = __builtin_fmaf(a[i], xb.x, acc[i][q*4+0]);
          acc[i][q*4+1] = __builtin_fmaf(a[i], xb.y, acc[i][q*4+1]);
          acc[i][q*4+2] = __builtin_fmaf(a[i], xb.z, acc[i][q*4+2]);
          acc[i][q*4+3] = __builtin_fmaf(a[i], xb.w, acc[i][q*4+3]);
        }
      }
    }

    if (more) {
      const int nb = cur ^ 1;
      STAGE(nb);      // overlaps other waves' compute; protected by next barrier
    }
    cur ^= 1;
  }
  #undef STAGE

  // epilogue: + bias (ref adds b once to xp — identical), coalesced float4 stores
  float4 bv[4];
  #pragma unroll
  for (int q = 0; q < 4; ++q) bv[q] = *(const float4*)&bias[n0 + 64*q + tx*4];
  #pragma unroll
  for (int i = 0; i < 8; ++i) {
    float* cp = C + (size_t)(m0 + ty*8 + i) * HID + n0 + tx*4;
    #pragma unroll
    for (int q = 0; q < 4; ++q) {
      const float4 v = {acc[i][q*4+0] + bv[q].x, acc[i][q*4+1] + bv[q].y,
                        acc[i][q*4+2] + bv[q].z, acc[i][q*4+3] + bv[q].w};
      *(float4*)(cp + 64*q) = v;
    }
  }
}

// ---------------- LIF scan: 2 neurons per thread (dual-chain ILP) ----------------
// v10: R8's wave-pipeline regressed (297us vs R3's 164): 4x VMEM instrs (64B/wave
// effective), shfl_up + predication in the critical chain, 3/4-divergent stores.
// REVERTED to R3 structure. New lever: R3-lif sits 3.8x above the ~43us issue floor —
// latency-chain-bound: one chain/wave (64 deps x ~4cyc = 256 cyc per t vs ~220
// issue-cyc) at 4 waves/SIMD leaves the VALU idle on any stall. Fix: each thread owns
// TWO neurons (idx, idx+BH/2), chains interleaved at substep granularity in source —
// 2 interleaved chains saturate a wave's issue slots alone (4-cyc dep / 2-cyc issue);
// loads stay perfectly coalesced. Also: accs dropped for layers 0-2 (as3 = layer-3
// accs only; others were computed-then-discarded) — pure instruction removal.
// Per-neuron-per-layer arithmetic chain is ORDER-IDENTICAL to reference -> absmax 0.0.
__device__ __forceinline__ void lif_step2(const float y0in, const float y1in,
                                          float v0[4], float v1[4],
                                          float av0[4], float av1[4],
                                          float& as0, float& as1) {
  float y0 = y0in, y1 = y1in;
  #pragma unroll
  for (int l = 0; l < 4; ++l) {
    float a0 = v0[l], a1 = v1[l];
    float accv0 = 0.f, accv1 = 0.f;
    float accs0 = 0.f, accs1 = 0.f;
    #pragma unroll
    for (int k = 0; k < 4; ++k) {
      const float d0 = y0 - a0;                      const float d1 = y1 - a1;
      a0 = __builtin_fmaf(d0, 0.5f, a0);             a1 = __builtin_fmaf(d1, 0.5f, a1);
      const float s0 = (a0 >= 1.0f) ? 1.0f : 0.0f;   const float s1 = (a1 >= 1.0f) ? 1.0f : 0.0f;
      a0 -= s0;                                      a1 -= s1;
      accv0 += a0;                                   accv1 += a1;
      if (l == 3) { accs0 += s0; accs1 += s1; }      // accs unused for l<3
    }
    v0[l] = a0; v1[l] = a1;
    const float m0 = accv0 * 0.25f;                  const float m1 = accv1 * 0.25f;
    av0[l] = m0; av1[l] = m1;
    y0 = m0; y1 = m1;                                // next layer consumes avg_v
    if (l == 3) { as0 = accs0; as1 = accs1; }
  }
}

__global__ __launch_bounds__(256) void lif_scan(
    const float* __restrict__ xp, float* __restrict__ outp, float* __restrict__ vstate,
    int tc, int first, int last) {
  const int idx  = blockIdx.x * 256 + threadIdx.x;   // neuron A
  const int idx2 = idx + BH / 2;                     // neuron B
  float v0[4], v1[4];
  if (first) {
    #pragma unroll
    for (int l = 0; l < 4; ++l) { v0[l] = 0.f; v1[l] = 0.f; }
  } else {
    #pragma unroll
    for (int l = 0; l < 4; ++l) {
      v0[l] = vstate[(size_t)l * BH + idx];
      v1[l] = vstate[(size_t)l * BH + idx2];
    }
  }
  float av0[4] = {0.f,0.f,0.f,0.f}, av1[4] = {0.f,0.f,0.f,0.f};
  const float* p0 = xp + idx;  const float* p1 = xp + idx2;
  float* o0 = outp + idx;      float* o1 = outp + idx2;

  if ((tc & 3) == 0 && tc >= 8) {
    // 4-deep per-neuron prefetch ring (8 loads in flight across both neurons).
    float c0[4], c1[4];
    #pragma unroll
    for (int i = 0; i < 4; ++i) {
      c0[i] = __builtin_nontemporal_load(&p0[(size_t)i * BH]);
      c1[i] = __builtin_nontemporal_load(&p1[(size_t)i * BH]);
    }
    for (int t = 0; t + 4 < tc; t += 4) {
      float n0[4], n1[4];
      #pragma unroll
      for (int i = 0; i < 4; ++i) {
        n0[i] = __builtin_nontemporal_load(&p0[(size_t)(i + 4) * BH]);
        n1[i] = __builtin_nontemporal_load(&p1[(size_t)(i + 4) * BH]);
      }
      #pragma unroll
      for (int i = 0; i < 4; ++i) {
        float as0, as1;
        lif_step2(c0[i], c1[i], v0, v1, av0, av1, as0, as1);
        __builtin_nontemporal_store(as0 * 0.25f, &o0[(size_t)i * BH]);
        __builtin_nontemporal_store(as1 * 0.25f, &o1[(size_t)i * BH]);
      }
      #pragma unroll
      for (int i = 0; i < 4; ++i) { c0[i] = n0[i]; c1[i] = n1[i]; }
      p0 += 4 * BH; p1 += 4 * BH; o0 += 4 * BH; o1 += 4 * BH;
    }
    #pragma unroll
    for (int i = 0; i < 4; ++i) {    // tail group, already in registers
      float as0, as1;
      lif_step2(c0[i], c1[i], v0, v1, av0, av1, as0, as1);
      __builtin_nontemporal_store(as0 * 0.25f, &o0[(size_t)i * BH]);
      __builtin_nontemporal_store(as1 * 0.25f, &o1[(size_t)i * BH]);
    }
  } else {
    for (int t = 0; t < tc; ++t) {
      float as0, as1;
      lif_step2(p0[0], p1[0], v0, v1, av0, av1, as0, as1);
      *o0 = as0 * 0.25f; *o1 = as1 * 0.25f;
      p0 += BH; p1 += BH; o0 += BH; o1 += BH;
    }
  }

  if (last) {
    #pragma unroll
    for (int l = 0; l < 4; ++l) {
      vstate[(size_t)l * BH + idx]  = av0[l];
      vstate[(size_t)l * BH + idx2] = av1[l];
    }
  } else {
    #pragma unroll
    for (int l = 0; l < 4; ++l) {
      vstate[(size_t)l * BH + idx]  = v0[l];
      vstate[(size_t)l * BH + idx2] = v1[l];
    }
  }
}

extern "C" void kernel_launch(void* const* d_in, const int* in_sizes, int n_in,
                              void* d_out, int out_size, void* d_ws, size_t ws_size,
                              hipStream_t stream) {
  const float* x = (const float*)d_in[0];   // [128,512,512] fp32
  const float* W = (const float*)d_in[1];   // [512,512] fp32
  const float* b = (const float*)d_in[2];   // [512] fp32
  float* out    = (float*)d_out;            // [128,512,512] avg spikes (fp32)
  float* states = out + (size_t)TT * BH;    // [4,512,512] final avg_v; also chunk-carry v

  int tc = TT;                              // xp chunk: tc MiB of ws
  while (tc > 1 && (size_t)tc * BH * 4ull > ws_size) tc >>= 1;
  float* xp = (float*)d_ws;
  const int nc = TT / tc;

  for (int c = 0; c < nc; ++c) {
    hipLaunchKernelGGL(gemm_f32, dim3(HID / 256, tc * BSZ / 128), dim3(256), 0, stream,
                       x + (size_t)c * tc * BH, W, b, xp);
    hipLaunchKernelGGL(lif_scan, dim3(BH / 512), dim3(256), 0, stream,
                       xp, out + (size_t)c * tc * BH, states,
                       tc, c == 0 ? 1 : 0, c == nc - 1 ? 1 : 0);
  }
}